// Round 1
// 501.654 us; speedup vs baseline: 1.1063x; 1.1063x over previous
//
#include <hip/hip_runtime.h>
#include <cstdint>
#include <cstddef>

#define NB 4
#define NT 8
#define NC 256
#define NDH 128
#define HWs 4096

typedef _Float16 f16;
typedef _Float16 f16x8 __attribute__((ext_vector_type(8)));
typedef float f32x16 __attribute__((ext_vector_type(16)));

// ============================================================================
// Workspace layout (bytes):
//  xh      @ 0          : 32*64*64*256 f16  = 67,108,864   x transposed [bt][h][w][c]
//  kbuf    @ 67108864   : 4*128*4096 f32    =  8,388,608   k NCHW
//  dots    @ 75497472   : 4*8*4096 f32      =    524,288   attn (softmax output)
//  parts   @ 76021760   : 8*4*128*4096 f16  = 33,554,432   per-t weighted v, NCHW
//    qpart  (aliased @ 76021760, dead before conv_v): 2*32*4096 f32 = 1 MB
//  pooledT @ 109576192  : 4*64*64*128 f16   =  4,194,304   pooled transposed [b][h][w][dh]
//  wq2     @ 113770496  : 589,824           weights [tap][cg][oc][8c] f16
//  wk2     @ 114360320  : 589,824
//  wv2     @ 114950144  : 589,824
//  wo2     @ 115539968  : 589,824
// ============================================================================

// async global->LDS, 16B per lane; LDS dest = wave-uniform base + lane*16
__device__ __forceinline__ void gload16(const void* g, void* l) {
    __builtin_amdgcn_global_load_lds(
        (const __attribute__((address_space(1))) void*)g,
        (__attribute__((address_space(3))) void*)l, 16, 0, 0);
}

// ---------------- prep: x (B,T,C,H,W) f32 -> xh [bt][h][w][c] f16 ------------
__global__ __launch_bounds__(256) void prep_x_kernel(const float* __restrict__ x,
                                                     f16* __restrict__ xh) {
    __shared__ f16 sxt[256 * 66];          // [c][w], stride 66 breaks bank conflicts
    int bt = blockIdx.x >> 6, h = blockIdx.x & 63;
    int tid = threadIdx.x;
    int w = tid & 63, c4 = tid >> 6;
    for (int p = 0; p < 64; ++p) {
        int c = p * 4 + c4;
        sxt[c * 66 + w] = (f16)x[(((size_t)bt * NC + c) * 64 + h) * 64 + w];
    }
    __syncthreads();
    int cg = tid & 31, wb = tid >> 5;      // wb 0..7
    f16x8* xh8 = (f16x8*)xh;
    for (int p = 0; p < 8; ++p) {
        int w2 = wb * 8 + p;
        f16x8 v;
        #pragma unroll
        for (int j = 0; j < 8; ++j) v[j] = sxt[(cg * 8 + j) * 66 + w2];
        xh8[((size_t)(bt * 64 + h) * 64 + w2) * 32 + cg] = v;
    }
}

// ---------------- prep: weights (OC,CIN,3,3) f32 -> [tap][cg][oc][8] f16 -----
__global__ __launch_bounds__(256) void prep_w_kernel(const float* __restrict__ w,
                                                     f16* __restrict__ wt2,
                                                     int OC, int CIN) {
    int CG = CIN >> 3;
    int idx = blockIdx.x * 256 + threadIdx.x;
    if (idx >= OC * CG) return;
    int oc = idx / CG, cg = idx - oc * CG;
    f16x8* wt8 = (f16x8*)wt2;
    #pragma unroll
    for (int tap = 0; tap < 9; ++tap) {
        f16x8 v;
        #pragma unroll
        for (int j = 0; j < 8; ++j)
            v[j] = (f16)w[((size_t)oc * CIN + cg * 8 + j) * 9 + tap];
        wt8[((size_t)tap * CG + cg) * OC + oc] = v;
    }
}

// ============================================================================
// conv core v2: implicit-GEMM 3x3 conv via mfma_f32_32x32x16_f16.
// Block tile: 64 oc x 8 output rows x 64 cols. 4 waves, wave wv owns rows
// {2wv, 2wv+1}; per wave acc[oi=2 oc-tiles][rr=2 rows][ct=2 col-tiles] f32x16.
// Double-buffered LDS, one barrier per K-step (16 ch), staging for step t+1
// issued via global_load_lds BEFORE step t's MFMAs (loads in flight under
// compute; drained by the vmcnt(0) at the end-of-step barrier).
// LDS x buf: [10 rows][cidx 0..65][s 0..1] f16x8; slot s holds channel group
//   cg0 + (s ^ ((cidx>>2)&1))  (swizzle -> conflict-free B-frag reads; the
//   swizzle is applied on the global SOURCE address, LDS dest stays linear)
// LDS w buf: [tap][q][64 oc] f16x8 (contiguous -> conflict-free A-frag reads)
// Fragment maps (gfx950): A[m=lane&31][k=8*(lane>>5)+j], B[k=8*(lane>>5)+j][n=lane&31],
// D: col=lane&31, row=(reg&3)+8*(reg>>2)+4*(lane>>5).
// ============================================================================
template <int CIN>
__device__ __forceinline__ void conv_core2(const f16x8* __restrict__ xh8,  // frame base
                                           const f16x8* __restrict__ wt8,
                                           int OCT, int oc0, int h0,
                                           f16x8* __restrict__ sxb,   // [2][10*132]
                                           f16x8* __restrict__ swb,   // [2][18*64]
                                           f32x16 acc[2][2][2]) {
    const int tid = threadIdx.x;
    const int lane = tid & 63;
    const int wv = tid >> 6;
    const int n = lane & 31, q = lane >> 5;
    const int CG = CIN / 8;
    const int NI = CIN / 16;

    #pragma unroll
    for (int oi = 0; oi < 2; ++oi)
        #pragma unroll
        for (int rr = 0; rr < 2; ++rr)
            #pragma unroll
            for (int ct = 0; ct < 2; ++ct)
                #pragma unroll
                for (int r = 0; r < 16; ++r) acc[oi][rr][ct][r] = 0.0f;

    f16x8 Z8 = {(f16)0, (f16)0, (f16)0, (f16)0, (f16)0, (f16)0, (f16)0, (f16)0};

    // One-time zeroing (persists across all K-steps, both buffers):
    //  - halo cols cidx=0,65 of every row
    //  - fully out-of-range rows (staging skips them below)
    #pragma unroll
    for (int bufi = 0; bufi < 2; ++bufi) {
        f16x8* sx8 = sxb + bufi * 1320;
        if (tid < 40) {
            int r = tid >> 2, k = tid & 3;
            sx8[r * 132 + (k >> 1) * 130 + (k & 1)] = Z8;
        }
        for (int r = 0; r < 10; ++r) {
            int h = h0 - 1 + r;
            if ((unsigned)h >= 64u && tid < 132) sx8[r * 132 + tid] = Z8;
        }
    }

    // async staging of one K-step (channel groups cg0, cg0+1) into (sx8, sw8)
    auto stage = [&](f16x8* sx8, f16x8* sw8, int cg0) {
        // weights: 18 wave-jobs x 1KB -> [tap][qh][64 oc]
        for (int j = wv; j < 18; j += 4) {
            int tap = j >> 1, qh = j & 1;
            gload16(wt8 + (size_t)(tap * CG + cg0 + qh) * OCT + oc0 + lane,
                    sw8 + (tap * 2 + qh) * 64);
        }
        // x rows: 20 wave-jobs x 1KB (row r, col-half cb); dest linear, source
        // carries the bank-conflict swizzle
        for (int j = wv; j < 20; j += 4) {
            int r = j >> 1, cb = j & 1;
            int h = h0 - 1 + r;
            if ((unsigned)h < 64u) {
                int col = cb * 32 + (lane >> 1);
                int cidx = col + 1;
                int cg = cg0 + ((lane & 1) ^ ((cidx >> 2) & 1));
                gload16(xh8 + (size_t)(h * 64 + col) * CG + cg,
                        sx8 + r * 132 + 2 + cb * 64);
            }
        }
    };

    stage(sxb, swb, 0);
    asm volatile("s_waitcnt vmcnt(0)" ::: "memory");
    __syncthreads();

    for (int it = 0; it < NI; ++it) {
        f16x8* sx8 = sxb + (it & 1) * 1320;
        f16x8* sw8 = swb + (it & 1) * 1152;
        // prefetch next K-step into the other buffer (in flight under MFMA)
        if (it + 1 < NI)
            stage(sxb + ((it + 1) & 1) * 1320, swb + ((it + 1) & 1) * 1152,
                  (it + 1) * 2);
        #pragma unroll
        for (int tap = 0; tap < 9; ++tap) {
            const int ky = tap / 3, kx = tap % 3;
            f16x8 a0 = sw8[(tap * 2 + q) * 64 + n];
            f16x8 a1 = sw8[(tap * 2 + q) * 64 + 32 + n];
            #pragma unroll
            for (int rr = 0; rr < 2; ++rr) {
                const int r = wv * 2 + rr + ky;
                #pragma unroll
                for (int ct = 0; ct < 2; ++ct) {
                    int cidx = ct * 32 + n + kx;
                    int s = q ^ ((cidx >> 2) & 1);
                    f16x8 b = sx8[r * 132 + cidx * 2 + s];
                    acc[0][rr][ct] = __builtin_amdgcn_mfma_f32_32x32x16_f16(a0, b, acc[0][rr][ct], 0, 0, 0);
                    acc[1][rr][ct] = __builtin_amdgcn_mfma_f32_32x32x16_f16(a1, b, acc[1][rr][ct], 0, 0, 0);
                }
            }
        }
        asm volatile("s_waitcnt vmcnt(0)" ::: "memory");
        __syncthreads();
    }
}

// ---------------- K1: k = conv(x[:,0], w_k) -> kbuf NCHW f32 -----------------
__global__ __launch_bounds__(256, 2) void conv_k_kernel(const f16* __restrict__ xh,
        const f16* __restrict__ wk2, float* __restrict__ kbuf) {
    __shared__ f16x8 sxb[2640];
    __shared__ f16x8 swb[2304];
    int bx = blockIdx.x;
    int b = bx >> 4, ocg = (bx >> 3) & 1, hb = bx & 7;
    int h0 = hb * 8, oc0 = ocg * 64;
    int bt = b * NT;   // t = 0
    f32x16 acc[2][2][2];
    conv_core2<NC>((const f16x8*)xh + (size_t)bt * 64 * 64 * 32, (const f16x8*)wk2,
                   NDH, oc0, h0, sxb, swb, acc);
    int lane = threadIdx.x & 63, wv = threadIdx.x >> 6;
    int n = lane & 31, q = lane >> 5;
    #pragma unroll
    for (int rr = 0; rr < 2; ++rr) {
        int h = h0 + wv * 2 + rr;
        #pragma unroll
        for (int oi = 0; oi < 2; ++oi)
            #pragma unroll
            for (int r = 0; r < 16; ++r) {
                int oc = oc0 + oi * 32 + 4 * q + (r & 3) + 8 * (r >> 2);
                float* kp = kbuf + ((size_t)(b * NDH + oc)) * HWs + h * 64;
                kp[n] = acc[oi][rr][0][r];
                kp[32 + n] = acc[oi][rr][1][r];
            }
    }
}

// ---------------- K2: qpart[ocg] = partial sum_dh conv_q(x[bt]) * k ----------
__global__ __launch_bounds__(256, 2) void conv_q_kernel(const f16* __restrict__ xh,
        const f16* __restrict__ wq2, const float* __restrict__ kbuf,
        float* __restrict__ qpart) {
    __shared__ f16x8 sxb[2640];
    __shared__ f16x8 swb[2304];
    int bx = blockIdx.x;
    int bt = bx >> 4, ocg = (bx >> 3) & 1, hb = bx & 7;
    int b = bt >> 3;
    int h0 = hb * 8, oc0 = ocg * 64;
    f32x16 acc[2][2][2];
    conv_core2<NC>((const f16x8*)xh + (size_t)bt * 64 * 64 * 32, (const f16x8*)wq2,
                   NDH, oc0, h0, sxb, swb, acc);
    int lane = threadIdx.x & 63, wv = threadIdx.x >> 6;
    int n = lane & 31, q = lane >> 5;
    #pragma unroll
    for (int rr = 0; rr < 2; ++rr) {
        int h = h0 + wv * 2 + rr;
        float p0 = 0.0f, p1 = 0.0f;
        #pragma unroll
        for (int oi = 0; oi < 2; ++oi)
            #pragma unroll
            for (int r = 0; r < 16; ++r) {
                int oc = oc0 + oi * 32 + 4 * q + (r & 3) + 8 * (r >> 2);
                const float* kp = kbuf + ((size_t)(b * NDH + oc)) * HWs + h * 64;
                p0 += acc[oi][rr][0][r] * kp[n];
                p1 += acc[oi][rr][1][r] * kp[32 + n];
            }
        p0 += __shfl_xor(p0, 32, 64);
        p1 += __shfl_xor(p1, 32, 64);
        if (q == 0) {
            qpart[((size_t)ocg * 32 + bt) * HWs + h * 64 + n] = p0;
            qpart[((size_t)ocg * 32 + bt) * HWs + h * 64 + 32 + n] = p1;
        }
    }
}

// ---------------- K3: softmax over T: dots = softmax(qpart0 + qpart1) --------
__global__ __launch_bounds__(256) void softmax_t_kernel(const float* __restrict__ qpart,
                                                        float* __restrict__ dots) {
    int idx = blockIdx.x * 256 + threadIdx.x;   // NB*HWs = 16384
    int b = idx >> 12;
    int p = idx & 4095;
    const float* q0 = qpart + (size_t)(b * NT) * HWs + p;
    const float* q1 = qpart + (size_t)(32 + b * NT) * HWs + p;
    float v[NT];
    float m = -3.4e38f;
    #pragma unroll
    for (int t = 0; t < NT; ++t) { v[t] = q0[t * HWs] + q1[t * HWs]; m = fmaxf(m, v[t]); }
    float s = 0.0f;
    #pragma unroll
    for (int t = 0; t < NT; ++t) { v[t] = __expf(v[t] - m); s += v[t]; }
    float inv = 1.0f / s;
    float* base = dots + (size_t)b * NT * HWs + p;
    #pragma unroll
    for (int t = 0; t < NT; ++t) base[t * HWs] = v[t] * inv;
}

// ---------------- K4: parts[t] = attn[t] * conv_v(x[b,t])  (f16 NCHW) --------
__global__ __launch_bounds__(256, 2) void conv_v_kernel(const f16* __restrict__ xh,
        const f16* __restrict__ wv2, const float* __restrict__ attn,
        f16* __restrict__ parts) {
    __shared__ f16x8 sxb[2640];
    __shared__ f16x8 swb[2304];
    int bx = blockIdx.x;
    int bt = bx >> 4, ocg = (bx >> 3) & 1, hb = bx & 7;
    int b = bt >> 3, t = bt & 7;
    int h0 = hb * 8, oc0 = ocg * 64;
    f32x16 acc[2][2][2];
    conv_core2<NC>((const f16x8*)xh + (size_t)bt * 64 * 64 * 32, (const f16x8*)wv2,
                   NDH, oc0, h0, sxb, swb, acc);
    int lane = threadIdx.x & 63, wv = threadIdx.x >> 6;
    int n = lane & 31, q = lane >> 5;
    f16* pp = parts + (size_t)(t * NB + b) * NDH * HWs;
    #pragma unroll
    for (int rr = 0; rr < 2; ++rr) {
        int h = h0 + wv * 2 + rr;
        float a0 = attn[(size_t)bt * HWs + h * 64 + n];
        float a1 = attn[(size_t)bt * HWs + h * 64 + 32 + n];
        #pragma unroll
        for (int oi = 0; oi < 2; ++oi)
            #pragma unroll
            for (int r = 0; r < 16; ++r) {
                int oc = oc0 + oi * 32 + 4 * q + (r & 3) + 8 * (r >> 2);
                f16* op = pp + (size_t)oc * HWs + h * 64;
                op[n] = (f16)(a0 * acc[oi][rr][0][r]);
                op[32 + n] = (f16)(a1 * acc[oi][rr][1][r]);
            }
    }
}

// ---------------- prep: pooled = sum_t parts -> pooledT [b][h][w][dh] f16 ----
__global__ __launch_bounds__(256) void prep_pooled_kernel(const f16* __restrict__ parts,
                                                          f16* __restrict__ pooledT) {
    __shared__ f16 sxt[128 * 66];
    int b = blockIdx.x >> 6, h = blockIdx.x & 63;
    int tid = threadIdx.x, w = tid & 63, c4 = tid >> 6;
    for (int p = 0; p < 32; ++p) {
        int c = p * 4 + c4;
        float s = 0.0f;
        #pragma unroll
        for (int t = 0; t < NT; ++t)
            s += (float)parts[(((size_t)(t * NB + b) * NDH + c)) * HWs + h * 64 + w];
        sxt[c * 66 + w] = (f16)s;
    }
    __syncthreads();
    int cg = tid & 15, wb = tid >> 4;  // wb 0..15
    f16x8* pt8 = (f16x8*)pooledT;
    for (int p = 0; p < 4; ++p) {
        int w2 = wb * 4 + p;
        f16x8 v;
        #pragma unroll
        for (int j = 0; j < 8; ++j) v[j] = sxt[(cg * 8 + j) * 66 + w2];
        pt8[((size_t)(b * 64 + h) * 64 + w2) * 16 + cg] = v;
    }
}

// ---------------- K5: out = conv(pooled, w_out) + bias, broadcast over T -----
__global__ __launch_bounds__(256, 2) void conv_out_kernel(const f16* __restrict__ pooledT,
        const f16* __restrict__ wo2, const float* __restrict__ b_out,
        float* __restrict__ out) {
    __shared__ f16x8 sxb[2640];
    __shared__ f16x8 swb[2304];
    int bx = blockIdx.x;
    int b = bx >> 5, ocg = (bx >> 3) & 3, hb = bx & 7;
    int h0 = hb * 8, oc0 = ocg * 64;
    f32x16 acc[2][2][2];
    conv_core2<NDH>((const f16x8*)pooledT + (size_t)b * 64 * 64 * 16, (const f16x8*)wo2,
                    NC, oc0, h0, sxb, swb, acc);
    int lane = threadIdx.x & 63, wv = threadIdx.x >> 6;
    int n = lane & 31, q = lane >> 5;
    #pragma unroll
    for (int rr = 0; rr < 2; ++rr) {
        int h = h0 + wv * 2 + rr;
        #pragma unroll
        for (int oi = 0; oi < 2; ++oi)
            #pragma unroll
            for (int r = 0; r < 16; ++r) {
                int oc = oc0 + oi * 32 + 4 * q + (r & 3) + 8 * (r >> 2);
                float bias = b_out[oc];
                float v0 = acc[oi][rr][0][r] + bias;
                float v1 = acc[oi][rr][1][r] + bias;
                for (int t = 0; t < NT; ++t) {
                    float* op = out + ((size_t)(b * NT + t) * NC + oc) * HWs + h * 64;
                    op[n] = v0;
                    op[32 + n] = v1;
                }
            }
    }
}

// ============================================================================
extern "C" void kernel_launch(void* const* d_in, const int* in_sizes, int n_in,
                              void* d_out, int out_size, void* d_ws, size_t ws_size,
                              hipStream_t stream) {
    (void)in_sizes; (void)n_in; (void)out_size; (void)ws_size;
    const float* x     = (const float*)d_in[0];
    const float* w_k   = (const float*)d_in[1];
    const float* w_q   = (const float*)d_in[2];
    const float* w_v   = (const float*)d_in[3];
    const float* w_out = (const float*)d_in[4];
    const float* b_out = (const float*)d_in[5];
    float* out = (float*)d_out;

    char* ws = (char*)d_ws;
    f16*   xh      = (f16*)ws;
    float* kbuf    = (float*)(ws + 67108864);
    float* dots    = (float*)(ws + 75497472);
    f16*   parts   = (f16*)(ws + 76021760);
    float* qpart   = (float*)(ws + 76021760);   // aliases parts; dead before conv_v
    f16*   pooledT = (f16*)(ws + 109576192);
    f16*   wq2     = (f16*)(ws + 113770496);
    f16*   wk2     = (f16*)(ws + 114360320);
    f16*   wv2     = (f16*)(ws + 114950144);
    f16*   wo2     = (f16*)(ws + 115539968);

    hipLaunchKernelGGL(prep_x_kernel, dim3(2048), dim3(256), 0, stream, x, xh);
    hipLaunchKernelGGL(prep_w_kernel, dim3(16), dim3(256), 0, stream, w_q, wq2, NDH, NC);
    hipLaunchKernelGGL(prep_w_kernel, dim3(16), dim3(256), 0, stream, w_k, wk2, NDH, NC);
    hipLaunchKernelGGL(prep_w_kernel, dim3(16), dim3(256), 0, stream, w_v, wv2, NDH, NC);
    hipLaunchKernelGGL(prep_w_kernel, dim3(16), dim3(256), 0, stream, w_out, wo2, NC, NDH);

    hipLaunchKernelGGL(conv_k_kernel, dim3(NB * 2 * 8), dim3(256), 0, stream, xh, wk2, kbuf);
    hipLaunchKernelGGL(conv_q_kernel, dim3(NB * NT * 2 * 8), dim3(256), 0, stream, xh, wq2, kbuf, qpart);
    hipLaunchKernelGGL(softmax_t_kernel, dim3(64), dim3(256), 0, stream, qpart, dots);
    hipLaunchKernelGGL(conv_v_kernel, dim3(NB * NT * 2 * 8), dim3(256), 0, stream, xh, wv2, dots, parts);
    hipLaunchKernelGGL(prep_pooled_kernel, dim3(256), dim3(256), 0, stream, parts, pooledT);
    hipLaunchKernelGGL(conv_out_kernel, dim3(NB * 4 * 8), dim3(256), 0, stream, pooledT, wo2, b_out, out);
}